// Round 11
// baseline (126.578 us; speedup 1.0000x reference)
//
#include <hip/hip_runtime.h>
#include <math.h>

// GaussianMixture log-likelihood: ll[n] = logsumexp_m( wlog[m] - dx^T G_m dx )
// arg(n,m) = c0 + c1*x0^2 + c2*x0 + c3*x1^2 + c4*x1 + c5*x0*x1  (log2-scaled)
// R11: remove online softmax in the fast path. A 64x64 table of min-dist^2
// to the mus over [0,1]^2 gives per-sample U = wl_min - lam2*Dtilde^2 (<=
// true max arg), so exp2(arg - U) never underflows the dominant term and a
// pk_min clamp at 120 guards overflow. Inner loop: 2 pk_fma + pk_sub +
// pk_min + pk_add + 2 exp per j -> no max tree, no rescale, no serial dep.
// Partials are plain sums; combine adds them and applies U.
// Model (fits R6-R10): VALU 2cyc + v_exp_f32 ~16cyc/wave64, additive issue.
// (R3: readfirstlane wave id -> scalar coeff loads. R5: any skipped-element
// max shortcut -> NaN; here there is NO max at all, U bound replaces it.
// R9: floor/cvt/ldexp are quarter-rate -> never poly-exp.)

#if __has_builtin(__builtin_amdgcn_exp2f)
#define EXP2(x) __builtin_amdgcn_exp2f(x)
#else
#define EXP2(x) exp2f(x)
#endif

typedef float v2f __attribute__((ext_vector_type(2)));
#define PKMAX(a, b) __builtin_elementwise_max(a, b)
#define PKMIN(a, b) __builtin_elementwise_min(a, b)

#define SPLIT 4     // waves per block (in-block M split)
#define YSPLIT 8    // gridDim.y M split
#define CH 16
#define GRID 64     // dmin-table resolution (64x64 over [0,1]^2)
#define NCELL (GRID * GRID)
#define USHIFT 25.0f
#define DCLAMP 120.0f
#define LN2 0.69314718055994530942f

// ---------------- prep: coefficient planes + header ----------------
// Header at C[6M..]: [0]=flag, [1..3]=cb1,cb3,cb5, [4]=wl_min(log2), [5]=lam2
__global__ __launch_bounds__(256) void prep_kernel(
    const float* __restrict__ mu,
    const float* __restrict__ A,
    const float* __restrict__ w,
    float* __restrict__ C,
    int M) {
  __shared__ float red[256];
  const int t = threadIdx.x;

  // redundant log-softmax normalizer over w (every block)
  float mx = -INFINITY;
  for (int m = t; m < M; m += 256) mx = fmaxf(mx, w[m]);
  red[t] = mx; __syncthreads();
  for (int s = 128; s > 0; s >>= 1) {
    if (t < s) red[t] = fmaxf(red[t], red[t + s]);
    __syncthreads();
  }
  const float wmax = red[0]; __syncthreads();

  float sum = 0.f;
  for (int m = t; m < M; m += 256) sum += expf(w[m] - wmax);
  red[t] = sum; __syncthreads();
  for (int s = 128; s > 0; s >>= 1) {
    if (t < s) red[t] += red[t + s];
    __syncthreads();
  }
  const float logZ = wmax + logf(red[0]);
  __syncthreads();

  const float LOG2E = 1.44269504088896340736f;
  const int Ms = M / gridDim.x;
  const int mlo = blockIdx.x * Ms, mhi = mlo + Ms;
  for (int m = mlo + t; m < mhi; m += 256) {
    const float a00 = A[m * 4 + 0], a01 = A[m * 4 + 1];
    const float a10 = A[m * 4 + 2], a11 = A[m * 4 + 3];
    const float g00 = 0.5f * (a00 * a00 + a01 * a01);
    const float g01 = 0.5f * (a00 * a10 + a01 * a11);
    const float g11 = 0.5f * (a10 * a10 + a11 * a11);
    const float g01s = 2.0f * g01;
    const float det = g00 * g11 - g01 * g01;
    const float wlog = (w[m] - logZ) + 0.5f * logf(det);
    const float mu0 = mu[m * 2 + 0], mu1 = mu[m * 2 + 1];
    const float c0 = wlog - (g00 * mu0 * mu0 + g01s * mu0 * mu1 + g11 * mu1 * mu1);
    const float c2 = 2.0f * g00 * mu0 + g01s * mu1;
    const float c4 = 2.0f * g11 * mu1 + g01s * mu0;
    C[0 * M + m] = LOG2E * c0;
    C[1 * M + m] = LOG2E * -g00;
    C[2 * M + m] = LOG2E * c2;
    C[3 * M + m] = LOG2E * -g11;
    C[4 * M + m] = LOG2E * c4;
    C[5 * M + m] = LOG2E * -g01s;
  }

  if (blockIdx.x == 0) {
    __shared__ int uni[256];
    __shared__ float rmin[256], rmax[256];
    const float r00 = A[0], r01 = A[1], r10 = A[2], r11 = A[3];
    const float rg00 = 0.5f * (r00 * r00 + r01 * r01);
    const float rg01 = 0.5f * (r00 * r10 + r01 * r11);
    const float rg11 = 0.5f * (r10 * r10 + r11 * r11);
    int myuni = 1;
    float wlmin = INFINITY, wlmax = -INFINITY;
    for (int m = t; m < M; m += 256) {
      const float a00 = A[m * 4 + 0], a01 = A[m * 4 + 1];
      const float a10 = A[m * 4 + 2], a11 = A[m * 4 + 3];
      const float g00 = 0.5f * (a00 * a00 + a01 * a01);
      const float g01 = 0.5f * (a00 * a10 + a01 * a11);
      const float g11 = 0.5f * (a10 * a10 + a11 * a11);
      myuni &= (g00 == rg00) & (g01 == rg01) & (g11 == rg11);
      const float det = g00 * g11 - g01 * g01;
      const float wl2 = LOG2E * ((w[m] - logZ) + 0.5f * logf(det));
      wlmin = fminf(wlmin, wl2);
      wlmax = fmaxf(wlmax, wl2);
    }
    uni[t] = myuni; rmin[t] = wlmin; rmax[t] = wlmax;
    __syncthreads();
    for (int s = 128; s > 0; s >>= 1) {
      if (t < s) {
        uni[t] &= uni[t + s];
        rmin[t] = fminf(rmin[t], rmin[t + s]);
        rmax[t] = fmaxf(rmax[t], rmax[t + s]);
      }
      __syncthreads();
    }
    if (t == 0) {
      // fast path requires uniform G AND small wlog spread (U-bound validity)
      ((int*)C)[6 * M + 0] = uni[0] && ((rmax[0] - rmin[0]) <= 20.0f);
      C[6 * M + 1] = LOG2E * -rg00;        // cb1
      C[6 * M + 2] = LOG2E * -rg11;        // cb3
      C[6 * M + 3] = LOG2E * -2.0f * rg01; // cb5
      C[6 * M + 4] = rmin[0];              // wl_min (log2 units)
      const float lmax = 0.5f * (rg00 + rg11) +
                         sqrtf(0.25f * (rg00 - rg11) * (rg00 - rg11) + rg01 * rg01);
      C[6 * M + 5] = LOG2E * lmax;         // lam2
    }
  }
}

// ---------------- table: min dist^2 to mus, 64x64 over [0,1]^2 -------------
// 256 blocks x 256 thr; block owns 16 cells; 16 threads/cell, 128 comps each.
// Deterministic, no atomics (each cell fully reduced within one block).
__global__ __launch_bounds__(256) void table_kernel(
    const float* __restrict__ mu,
    float* __restrict__ table,
    int M) {
  __shared__ float red[16][17];
  const int t = threadIdx.x;
  const int cl = t & 15;
  const int sl = t >> 4;
  const int cell = blockIdx.x * 16 + cl;
  const float cx = ((cell & (GRID - 1)) + 0.5f) * (1.0f / GRID);
  const float cy = ((cell >> 6) + 0.5f) * (1.0f / GRID);
  const int per = M / 16;
  float mn = 1e30f;
  for (int m = sl * per; m < (sl + 1) * per; ++m) {
    const float dx = cx - mu[2 * m], dy = cy - mu[2 * m + 1];
    mn = fminf(mn, fmaf(dx, dx, dy * dy));
  }
  red[cl][sl] = mn; __syncthreads();
  if (sl == 0) {
    float v = red[cl][0];
#pragma unroll
    for (int i = 1; i < 16; ++i) v = fminf(v, red[cl][i]);
    table[cell] = v;
  }
}

// ---------------- main kernel ----------------
// Block = 256 thr = 4 waves, 128 samples (lane l -> base+l, +64).
// Wave v + blockIdx.y y -> comps [(y*4+v)*64, +64) (4 chunks, fully unrolled).
__global__ __launch_bounds__(256) void gmix_kernel(
    const float* __restrict__ sample,
    const float* __restrict__ C,
    const float* __restrict__ table,
    float* __restrict__ P,
    float* __restrict__ Uarr,
    int N, int M) {
  __shared__ float Lsm[SPLIT][2][64];
  __shared__ float Lmx[SPLIT][2][64];

  const int lane = threadIdx.x & 63;
  const int wave = __builtin_amdgcn_readfirstlane((int)(threadIdx.x >> 6));
  const int nA = blockIdx.x * 128 + lane;
  const int nB = nA + 64;

  const float2 xA = (nA < N) ? ((const float2*)sample)[nA] : make_float2(0.f, 0.f);
  const float2 xB = (nB < N) ? ((const float2*)sample)[nB] : make_float2(0.f, 0.f);
  const v2f x0p = {xA.x, xB.x};
  const v2f x1p = {xA.y, xB.y};

  const int flag = ((const int*)C)[6 * M + 0];
  const float cb1 = C[6 * M + 1];
  const float cb3 = C[6 * M + 2];
  const float cb5 = C[6 * M + 3];

  const int Mq = M / (SPLIT * YSPLIT);
  const int m0 = (blockIdx.y * SPLIT + wave) * Mq;   // SGPR -> scalar loads
  const float* __restrict__ C0 = C + m0;
  const float* __restrict__ C1 = C + M + m0;
  const float* __restrict__ C2 = C + 2 * M + m0;
  const float* __restrict__ C3 = C + 3 * M + m0;
  const float* __restrict__ C4 = C + 4 * M + m0;
  const float* __restrict__ C5 = C + 5 * M + m0;

  if (flag) {
    const float wl = C[6 * M + 4];
    const float lam = C[6 * M + 5];
    const v2f basep = cb1 * x0p * x0p + cb3 * x1p * x1p + cb5 * x0p * x1p;

    // per-sample shift U: wl - lam*Dtilde^2 + USHIFT, Dtilde >= dist-to-
    // nearest-mu via clamped point + table lookup + cell margin.
    float Uf[2];
#pragma unroll
    for (int k = 0; k < 2; ++k) {
      const float sx0 = (k == 0) ? xA.x : xB.x;
      const float sx1 = (k == 0) ? xA.y : xB.y;
      const float px = fminf(fmaxf(sx0, 0.f), 1.f);
      const float py = fminf(fmaxf(sx1, 0.f), 1.f);
      const int ix = (int)fminf(px * GRID, GRID - 1.0f);
      const int iy = (int)fminf(py * GRID, GRID - 1.0f);
      const float dc = sqrtf(table[iy * GRID + ix]);
      const float dx = sx0 - px, dy = sx1 - py;
      const float rr = sqrtf(fmaf(dx, dx, dy * dy));
      const float D = rr + dc + 0.012f;          // cell center->corner margin
      Uf[k] = wl - lam * D * D + USHIFT;
    }
    const v2f V = {Uf[0] - basep.x, Uf[1] - basep.y};
    const v2f dcl = {DCLAMP, DCLAMP};

    v2f acc0 = {0.f, 0.f}, acc1 = {0.f, 0.f}, acc2 = {0.f, 0.f}, acc3 = {0.f, 0.f};
#pragma unroll
    for (int m = 0; m < 64; m += CH) {
      float c0r[CH], c2r[CH], c4r[CH];
#pragma unroll
      for (int j = 0; j < CH; ++j) {
        c0r[j] = C0[m + j]; c2r[j] = C2[m + j]; c4r[j] = C4[m + j];
      }
#pragma unroll
      for (int j = 0; j < CH; ++j) {
        const v2f t = x0p * c2r[j] + c0r[j];     // v_pk_fma_f32
        const v2f a = x1p * c4r[j] + t;          // v_pk_fma_f32
        const v2f d = PKMIN(a - V, dcl);         // pk_add + pk_min (overflow guard)
        v2f e;
        e.x = EXP2(d.x);
        e.y = EXP2(d.y);
        if ((j & 3) == 0) acc0 += e;
        else if ((j & 3) == 1) acc1 += e;
        else if ((j & 3) == 2) acc2 += e;
        else acc3 += e;
      }
    }
    const v2f S2 = (acc0 + acc1) + (acc2 + acc3);

    Lsm[wave][0][lane] = S2.x;
    Lsm[wave][1][lane] = S2.y;
    __syncthreads();

    if (wave < 2) {
      const int set = wave;
      const int n = blockIdx.x * 128 + set * 64 + lane;
      if (n < N) {
        float S = Lsm[0][set][lane];
#pragma unroll
        for (int v = 1; v < SPLIT; ++v) S += Lsm[v][set][lane];
        P[blockIdx.y * N + n] = S;               // plain partial sum
        if (blockIdx.y == 0) Uarr[n] = Uf[set];  // shared shift for combine
      }
    }
  } else {
    // generic fallback: R10's online-softmax path (log2-domain partials)
    v2f basep = cb1 * x0p * x0p + cb3 * x1p * x1p + cb5 * x0p * x1p;
    float mxA = -INFINITY, sA = 0.0f;
    float mxB = -INFINITY, sB = 0.0f;
    for (int m = 0; m < Mq; m += CH) {
      v2f a[CH];
#pragma unroll
      for (int j = 0; j < CH; ++j) {
        const float c0 = C0[m + j], c1 = C1[m + j], c2 = C2[m + j];
        const float c3 = C3[m + j], c4 = C4[m + j], c5 = C5[m + j];
        v2f t0 = x0p * c1 + c2;
        t0 = x1p * c5 + t0;
        v2f t1 = x1p * c3 + c4;
        v2f r = t0 * x0p + c0;
        a[j] = t1 * x1p + r;
      }
      v2f cm01 = PKMAX(a[0], a[1]);
      v2f cm23 = PKMAX(a[2], a[3]);
      v2f cm45 = PKMAX(a[4], a[5]);
      v2f cm67 = PKMAX(a[6], a[7]);
#pragma unroll
      for (int j = 8; j < CH; j += 4) {
        cm01 = PKMAX(cm01, a[j]);
        cm23 = PKMAX(cm23, a[j + 1]);
        cm45 = PKMAX(cm45, a[j + 2]);
        cm67 = PKMAX(cm67, a[j + 3]);
      }
      const v2f cm = PKMAX(PKMAX(cm01, cm23), PKMAX(cm45, cm67));
      const float nmA = fmaxf(mxA, cm.x);
      const float nmB = fmaxf(mxB, cm.y);
      sA *= EXP2(mxA - nmA);
      sB *= EXP2(mxB - nmB);
      const v2f nmp = {nmA, nmB};
      float lA0 = 0.f, lA1 = 0.f, lB0 = 0.f, lB1 = 0.f;
#pragma unroll
      for (int j = 0; j < CH; j += 2) {
        const v2f d0 = a[j] - nmp;
        const v2f d1 = a[j + 1] - nmp;
        lA0 += EXP2(d0.x);
        lB0 += EXP2(d0.y);
        lA1 += EXP2(d1.x);
        lB1 += EXP2(d1.y);
      }
      sA += lA0 + lA1; mxA = nmA;
      sB += lB0 + lB1; mxB = nmB;
    }
    Lmx[wave][0][lane] = mxA + basep.x; Lsm[wave][0][lane] = sA;
    Lmx[wave][1][lane] = mxB + basep.y; Lsm[wave][1][lane] = sB;
    __syncthreads();
    if (wave < 2) {
      const int set = wave;
      const int n = blockIdx.x * 128 + set * 64 + lane;
      if (n < N) {
        float gm = Lmx[0][set][lane];
#pragma unroll
        for (int v = 1; v < SPLIT; ++v) gm = fmaxf(gm, Lmx[v][set][lane]);
        float S = 0.f;
#pragma unroll
        for (int v = 0; v < SPLIT; ++v)
          S += Lsm[v][set][lane] * EXP2(Lmx[v][set][lane] - gm);
        P[blockIdx.y * N + n] = gm + __log2f(S);
      }
    }
  }
}

__global__ __launch_bounds__(256) void combine_kernel(
    const float* __restrict__ P,
    const float* __restrict__ Uarr,
    const float* __restrict__ C,
    float* __restrict__ out,
    int N, int M) {
  const int n = blockIdx.x * blockDim.x + threadIdx.x;
  if (n >= N) return;
  const int flag = ((const int*)C)[6 * M + 0];
  if (flag) {
    float S = 0.f;
#pragma unroll
    for (int y = 0; y < YSPLIT; ++y) S += P[y * N + n];
    out[n] = (Uarr[n] + __log2f(S)) * LN2;
  } else {
    float p[YSPLIT];
#pragma unroll
    for (int y = 0; y < YSPLIT; ++y) p[y] = P[y * N + n];
    float mx = p[0];
#pragma unroll
    for (int y = 1; y < YSPLIT; ++y) mx = fmaxf(mx, p[y]);
    float S0 = 0.f, S1 = 0.f;
#pragma unroll
    for (int y = 0; y < YSPLIT; y += 2) {
      S0 += EXP2(p[y] - mx);
      S1 += EXP2(p[y + 1] - mx);
    }
    out[n] = (mx + __log2f(S0 + S1)) * LN2;
  }
}

extern "C" void kernel_launch(void* const* d_in, const int* in_sizes, int n_in,
                              void* d_out, int out_size, void* d_ws, size_t ws_size,
                              hipStream_t stream) {
  const float* sample = (const float*)d_in[0];
  const float* mu     = (const float*)d_in[1];
  const float* A      = (const float*)d_in[2];
  const float* w      = (const float*)d_in[3];
  float* out = (float*)d_out;

  const int N = in_sizes[0] / 2;   // sample is (N,2)
  const int M = in_sizes[3];       // w is (M,1)

  float* C     = (float*)d_ws;                    // 6*M + 16 header
  float* table = C + 6 * M + 16;                  // NCELL floats (16 KB)
  float* P     = table + NCELL;                   // YSPLIT*N floats
  float* Uarr  = P + YSPLIT * N;                  // N floats

  prep_kernel<<<8, 256, 0, stream>>>(mu, A, w, C, M);
  table_kernel<<<NCELL / 16, 256, 0, stream>>>(mu, table, M);
  dim3 grid((N + 127) / 128, YSPLIT);
  gmix_kernel<<<grid, 256, 0, stream>>>(sample, C, table, P, Uarr, N, M);
  combine_kernel<<<(N + 255) / 256, 256, 0, stream>>>(P, Uarr, C, out, N, M);
}